// Round 7
// baseline (105.850 us; speedup 1.0000x reference)
//
#include <hip/hip_runtime.h>
#include <math.h>

#define Bv 32
#define Tv 256
#define Vv 32000
#define QTR 8000                 // floats per quarter-row
#define NBLK (4 * Bv * Tv)       // 32768 blocks, four per row, bid-major (contiguous)

__device__ __forceinline__ float exp4(float4 v) {
    return __expf(v.x) + __expf(v.y) + __expf(v.z) + __expf(v.w);
}

// Four blocks per (b,t) row, bid-major: consecutive bids read contiguous memory.
// q=0 block prefetches x_gt BEFORE the stream so the gather latency hides.
__global__ __launch_bounds__(256) void row_partial_kernel(const float* __restrict__ pred,
                                                          const int*   __restrict__ gt,
                                                          const int*   __restrict__ lens,
                                                          float*       __restrict__ partial,
                                                          float*       __restrict__ xg) {
    const int bid = blockIdx.x;          // [0, 4*B*T)
    const int r   = bid >> 2;            // row
    const int q   = bid & 3;             // quarter
    const int b   = r >> 8;              // T = 256
    const int t   = r & 255;
    const int tid = threadIdx.x;

    if (t >= lens[b] - 1) return;        // masked row: finalize skips it

    // prefetch the target logit early (q==0, tid==0 only); latency hides under stream
    float xgv = 0.0f;
    if (q == 0 && tid == 0) xgv = pred[(size_t)r * Vv + gt[r]];

    const float4* seg = reinterpret_cast<const float4*>(pred + (size_t)r * Vv + q * QTR);

    // 2000 float4 = 3*512 + 256 + 208, all static bounds -> deep load pipelining
    float s0 = 0.0f, s1 = 0.0f;
    #pragma unroll
    for (int k = 0; k < 3; ++k) {
        float4 a = seg[tid + 512 * k];
        float4 c = seg[tid + 256 + 512 * k];
        s0 += exp4(a);
        s1 += exp4(c);
    }
    { float4 a = seg[tid + 1536]; s0 += exp4(a); }
    if (tid < 208) { float4 a = seg[tid + 1792]; s1 += exp4(a); }
    float s = s0 + s1;

    __shared__ float red[4];
    const int wave = tid >> 6;
    const int lane = tid & 63;
    #pragma unroll
    for (int off = 32; off; off >>= 1) s += __shfl_xor(s, off);
    if (lane == 0) red[wave] = s;
    __syncthreads();
    if (tid == 0) {
        partial[bid] = red[0] + red[1] + red[2] + red[3];
        if (q == 0) xg[r] = xgv;
    }
}

// Single-block deterministic reduction:
//   loss = sum_valid( log(p0+p1+p2+p3) - xg ) / max(sum(max(len-1,0)), 1)
__global__ __launch_bounds__(256) void finalize_kernel(const float* __restrict__ partial,
                                                       const float* __restrict__ xg,
                                                       const int*   __restrict__ lens,
                                                       float*       __restrict__ out) {
    const int tid = threadIdx.x;
    float s = 0.0f;
    for (int r = tid; r < Bv * Tv; r += 256) {
        const int b = r >> 8;
        const int t = r & 255;
        if (t < lens[b] - 1) {
            float p = partial[4 * r] + partial[4 * r + 1]
                    + partial[4 * r + 2] + partial[4 * r + 3];
            s += logf(p) - xg[r];
        }
    }

    __shared__ float red[4];
    const int wave = tid >> 6;
    const int lane = tid & 63;
    #pragma unroll
    for (int off = 32; off; off >>= 1) s += __shfl_xor(s, off);
    if (lane == 0) red[wave] = s;
    __syncthreads();
    if (tid == 0) {
        float ss = red[0] + red[1] + red[2] + red[3];
        long long cnt = 0;
        for (int bb = 0; bb < Bv; ++bb) {
            int c = lens[bb] - 1;
            if (c > 0) cnt += c;
        }
        if (cnt < 1) cnt = 1;
        out[0] = ss / (float)cnt;
    }
}

extern "C" void kernel_launch(void* const* d_in, const int* in_sizes, int n_in,
                              void* d_out, int out_size, void* d_ws, size_t ws_size,
                              hipStream_t stream) {
    const float* pred = (const float*)d_in[0];
    const int*   gt   = (const int*)d_in[1];
    const int*   lens = (const int*)d_in[2];
    float*       out  = (float*)d_out;
    float*       partial = (float*)d_ws;                   // NBLK floats = 128 KiB
    float*       xg      = (float*)d_ws + NBLK;            // B*T floats  =  32 KiB

    row_partial_kernel<<<NBLK, 256, 0, stream>>>(pred, gt, lens, partial, xg);
    finalize_kernel<<<1, 256, 0, stream>>>(partial, xg, lens, out);
}